// Round 6
// baseline (674.659 us; speedup 1.0000x reference)
//
#include <hip/hip_runtime.h>
#include <hip/hip_bf16.h>

#define VOUT 50257
#define KHOT 1024
#define DIM  1024
#define RHOT 384
#define RCOLD 32
#define RF   416   // RHOT + RCOLD

typedef __attribute__((ext_vector_type(8))) short short8;
typedef __attribute__((ext_vector_type(4))) float f32x4;

// ---------------- K0: convert f32 weights to bf16 ----------------
__global__ void k_convert(const float* __restrict__ Bh, const float* __restrict__ Bc,
                          const float* __restrict__ Uh, const float* __restrict__ Uc,
                          __hip_bfloat16* __restrict__ Bmat,
                          __hip_bfloat16* __restrict__ UhB,
                          __hip_bfloat16* __restrict__ UcB) {
  const int nBh = RHOT * DIM;            // 393216
  const int nBm = RF * DIM;              // 425984
  const int nUh = KHOT * RHOT;           // 393216
  const int nUc = (VOUT - KHOT) * RCOLD; // 1575456
  const int total = nBm + nUh + nUc;
  for (int i = blockIdx.x * blockDim.x + threadIdx.x; i < total;
       i += gridDim.x * blockDim.x) {
    if (i < nBm) {
      float v = (i < nBh) ? Bh[i] : Bc[i - nBh];
      Bmat[i] = __float2bfloat16(v);
    } else if (i < nBm + nUh) {
      UhB[i - nBm] = __float2bfloat16(Uh[i - nBm]);
    } else {
      int j = i - nBm - nUh;
      UcB[j] = __float2bfloat16(Uc[j]);
    }
  }
}

// ---------------- K1: G = Bmat @ Bmat^T  (416x416, K=1024), f32 out ----------------
__global__ __launch_bounds__(256) void k_gram(const __hip_bfloat16* __restrict__ Bmat,
                                              float* __restrict__ G) {
  const int wave = threadIdx.x >> 6;
  const int lane = threadIdx.x & 63;
  const int idx = blockIdx.x * 4 + wave;
  if (idx >= 26 * 26) return;  // wave-uniform
  const int ti = idx / 26, tj = idx % 26;
  const int i0 = ti * 16, j0 = tj * 16;
  const int col16 = lane & 15;
  const int g4 = lane >> 4;

  f32x4 acc = (f32x4){0.f, 0.f, 0.f, 0.f};
  const __hip_bfloat16* arow = Bmat + (size_t)(i0 + col16) * DIM;
  const __hip_bfloat16* brow = Bmat + (size_t)(j0 + col16) * DIM;
#pragma unroll 4
  for (int ks = 0; ks < DIM / 32; ++ks) {
    short8 a = *reinterpret_cast<const short8*>(arow + ks * 32 + g4 * 8);
    short8 b = *reinterpret_cast<const short8*>(brow + ks * 32 + g4 * 8);
    acc = __builtin_amdgcn_mfma_f32_16x16x32_bf16(a, b, acc, 0, 0, 0);
  }
#pragma unroll
  for (int r = 0; r < 4; ++r)
    G[(size_t)(i0 + g4 * 4 + r) * RF + j0 + col16] = acc[r];
}

// ---------------- K2: per-token F[n] = u @ G  (f32 math, bf16 out) ----------------
__global__ void k_encode(const int* __restrict__ tokens, const int* __restrict__ o2n,
                         const float* __restrict__ Uh, const float* __restrict__ Uc,
                         const float* __restrict__ G, __hip_bfloat16* __restrict__ F) {
  const int n = blockIdx.x;
  __shared__ float u[RHOT];
  const int tok = tokens[n];
  const int tn = o2n[tok];
  const bool hot = tn < KHOT;
  const int R = hot ? RHOT : RCOLD;
  const float* urow = hot ? (Uh + (size_t)tn * RHOT) : (Uc + (size_t)(tn - KHOT) * RCOLD);
  for (int r = threadIdx.x; r < R; r += blockDim.x) u[r] = urow[r];
  __syncthreads();
  const int gbase = hot ? 0 : RHOT;
  for (int c = threadIdx.x; c < RF; c += blockDim.x) {
    float acc = 0.f;
    for (int r = 0; r < R; ++r) acc += u[r] * G[(size_t)(gbase + r) * RF + c];
    F[(size_t)n * RF + c] = __float2bfloat16(acc);
  }
}

// ---------------- K3 v6: one block owns 16 FULL output rows ----------------
// Grid = 256 blocks (N/16). Block sweeps 99 col-windows of 512 in order; wave w
// owns the 128-col slice [win*512 + w*128, +128) = 8 MFMA col-subtiles.
// Per window: 8 cold MFMA (K=32) from LDS-staged F, per-wave PRIVATE LDS
// transpose (no barriers in loop), dwordx4 stores (512B contiguous per 32-lane
// half). Each row's 201KB is written sequentially in time by one block ->
// window-boundary lines merge in L2 -> write amplification ~1.0, no RMW.
#define CW 512   // cols per window
#define WW 128   // cols per wave
#define RPB 16   // rows per block
#define FPITCH 424  // Fs LDS pitch in bf16 (row stride 848B -> ~2-way conflicts)

__global__ __launch_bounds__(256) void k_out(const int* __restrict__ o2n,
                                             const __hip_bfloat16* __restrict__ F,
                                             const __hip_bfloat16* __restrict__ Uh,
                                             const __hip_bfloat16* __restrict__ Uc,
                                             const float* __restrict__ log_alpha,
                                             const float* __restrict__ bias,
                                             float* __restrict__ out) {
  __shared__ __hip_bfloat16 Fs[RPB][FPITCH];  // full F slice for 16 rows (13.6 KB)
  __shared__ float Epi[4][16][132];           // per-wave private transpose (33.8 KB)
  const int tid = threadIdx.x;
  const int wave = tid >> 6;
  const int lane = tid & 63;
  const int col16 = lane & 15;
  const int g4 = lane >> 4;
  const int lq = lane & 31;   // store lane-in-half
  const int lh = lane >> 5;   // store half (row parity)
  const int n0 = blockIdx.x * RPB;
  const float alpha = expf(log_alpha[0]);
  const short8 zero8 = (short8){0, 0, 0, 0, 0, 0, 0, 0};

  // stage F slice: 16 rows x 416 cols (52 short8-chunks per row)
  for (int idx = tid; idx < RPB * 52; idx += 256) {
    const int row = idx / 52, ch = idx % 52;
    *reinterpret_cast<short8*>(&Fs[row][ch * 8]) =
        *reinterpret_cast<const short8*>(F + (size_t)(n0 + row) * RF + ch * 8);
  }
  __syncthreads();

  const int NW = (VOUT + CW - 1) / CW;  // 99

  // metadata for window 0 (double-buffered one window ahead)
  int cs[8];
  f32x4 cb4;
  {
    const int c0w = wave * WW;
#pragma unroll
    for (int s = 0; s < 8; ++s) {
      const int v = c0w + s * 16 + col16;
      cs[s] = o2n[(v < VOUT) ? v : (VOUT - 1)];
    }
    const int cl = c0w + lq * 4;
    if (cl + 3 < VOUT) cb4 = *reinterpret_cast<const f32x4*>(bias + cl);
    else {
#pragma unroll
      for (int j = 0; j < 4; ++j) cb4[j] = bias[(cl + j < VOUT) ? cl + j : (VOUT - 1)];
    }
  }

  for (int win = 0; win < NW; ++win) {
    const int c0w = win * CW + wave * WW;

    // prefetch next window's metadata (hides L2 latency under this window)
    int ns[8];
    f32x4 nb4;
    if (win + 1 < NW) {
      const int c1 = (win + 1) * CW + wave * WW;
#pragma unroll
      for (int s = 0; s < 8; ++s) {
        const int v = c1 + s * 16 + col16;
        ns[s] = o2n[(v < VOUT) ? v : (VOUT - 1)];
      }
      const int cl = c1 + lq * 4;
      if (cl + 3 < VOUT) nb4 = *reinterpret_cast<const f32x4*>(bias + cl);
      else {
#pragma unroll
        for (int j = 0; j < 4; ++j) nb4[j] = bias[(cl + j < VOUT) ? cl + j : (VOUT - 1)];
      }
    } else {
#pragma unroll
      for (int s = 0; s < 8; ++s) ns[s] = cs[s];
      nb4 = cb4;
    }

    unsigned hotm = 0, coldm = 0;
#pragma unroll
    for (int s = 0; s < 8; ++s) {
      if (__any(cs[s] < KHOT)) hotm |= (1u << s);
      if (__any(cs[s] >= KHOT)) coldm |= (1u << s);
    }

    f32x4 acc[8];
#pragma unroll
    for (int s = 0; s < 8; ++s) acc[s] = (f32x4){0.f, 0.f, 0.f, 0.f};

    // cold contribution: K = 32, A-frag from LDS Fs (shared across subtiles)
    {
      const short8 afc = *reinterpret_cast<const short8*>(&Fs[col16][RHOT + g4 * 8]);
#pragma unroll
      for (int s = 0; s < 8; ++s) {
        if (coldm & (1u << s)) {
          short8 bfrag = zero8;
          if (cs[s] >= KHOT)
            bfrag = *reinterpret_cast<const short8*>(
                Uc + (size_t)(cs[s] - KHOT) * RCOLD + g4 * 8);
          acc[s] = __builtin_amdgcn_mfma_f32_16x16x32_bf16(afc, bfrag, acc[s], 0, 0, 0);
        }
      }
    }
    // hot contribution: K = 384 (only windows containing hot columns)
    if (hotm) {
      for (int ks = 0; ks < RHOT / 32; ++ks) {
        const short8 afh = *reinterpret_cast<const short8*>(&Fs[col16][ks * 32 + g4 * 8]);
#pragma unroll
        for (int s = 0; s < 8; ++s) {
          if (hotm & (1u << s)) {
            short8 bfrag = zero8;
            if (cs[s] < KHOT)
              bfrag = *reinterpret_cast<const short8*>(
                  Uh + (size_t)cs[s] * RHOT + ks * 32 + g4 * 8);
            acc[s] = __builtin_amdgcn_mfma_f32_16x16x32_bf16(afh, bfrag, acc[s], 0, 0, 0);
          }
        }
      }
    }

    // per-wave private LDS transpose (no barriers; lgkmcnt orders cross-lane RAW)
#pragma unroll
    for (int s = 0; s < 8; ++s)
#pragma unroll
      for (int r = 0; r < 4; ++r)
        Epi[wave][g4 * 4 + r][s * 16 + col16] = acc[s][r];
    asm volatile("s_waitcnt lgkmcnt(0)" ::: "memory");

    // stores: 8 insts, each covers rows {2i, 2i+1}, 512B contiguous per half
#pragma unroll
    for (int i = 0; i < 8; ++i) {
      const int row = 2 * i + lh;
      f32x4 vals = *reinterpret_cast<const f32x4*>(&Epi[wave][row][lq * 4]);
      const int c = c0w + lq * 4;
      const size_t gr = (size_t)(n0 + row) * VOUT;
      vals = vals * alpha + cb4;
      if (c + 3 < VOUT) {
        *reinterpret_cast<f32x4*>(out + gr + c) = vals;
      } else {
#pragma unroll
        for (int j = 0; j < 4; ++j)
          if (c + j < VOUT) out[gr + c + j] = vals[j];
      }
    }

    // rotate metadata
#pragma unroll
    for (int s = 0; s < 8; ++s) cs[s] = ns[s];
    cb4 = nb4;
  }
}

extern "C" void kernel_launch(void* const* d_in, const int* in_sizes, int n_in,
                              void* d_out, int out_size, void* d_ws, size_t ws_size,
                              hipStream_t stream) {
  const int* tokens    = (const int*)d_in[0];
  const int* o2n       = (const int*)d_in[1];
  const float* B_hot   = (const float*)d_in[2];
  const float* B_cold  = (const float*)d_in[3];
  const float* U_hot   = (const float*)d_in[4];
  const float* U_cold  = (const float*)d_in[5];
  const float* log_a   = (const float*)d_in[6];
  const float* bias    = (const float*)d_in[7];
  float* out = (float*)d_out;

  const int N = in_sizes[0];  // 4096 tokens

  // workspace layout (bytes)
  char* ws = (char*)d_ws;
  __hip_bfloat16* Bmat = (__hip_bfloat16*)(ws + 0);             // 425984*2
  __hip_bfloat16* UhB  = (__hip_bfloat16*)(ws + (1u << 20));    // 393216*2
  __hip_bfloat16* UcB  = (__hip_bfloat16*)(ws + (2u << 20));    // 1575456*2
  float*          G    = (float*)(ws + (6u << 20));             // 416*416*4
  __hip_bfloat16* F    = (__hip_bfloat16*)(ws + (7u << 20));    // 4096*416*2

  k_convert<<<2048, 256, 0, stream>>>(B_hot, B_cold, U_hot, U_cold, Bmat, UhB, UcB);
  k_gram<<<169, 256, 0, stream>>>(Bmat, G);
  k_encode<<<N, 256, 0, stream>>>(tokens, o2n, U_hot, U_cold, G, F);

  k_out<<<N / RPB, 256, 0, stream>>>(o2n, F, UhB, UcB, log_a, bias, out);
}

// Round 7
// 436.264 us; speedup vs baseline: 1.5464x; 1.5464x over previous
//
#include <hip/hip_runtime.h>
#include <hip/hip_bf16.h>

#define VOUT 50257
#define KHOT 1024
#define DIM  1024
#define RHOT 384
#define RCOLD 32
#define RF   416   // RHOT + RCOLD

typedef __attribute__((ext_vector_type(8))) short short8;
typedef __attribute__((ext_vector_type(4))) float f32x4;

// ---------------- K0: convert f32 weights to bf16 ----------------
__global__ void k_convert(const float* __restrict__ Bh, const float* __restrict__ Bc,
                          const float* __restrict__ Uh, const float* __restrict__ Uc,
                          __hip_bfloat16* __restrict__ Bmat,
                          __hip_bfloat16* __restrict__ UhB,
                          __hip_bfloat16* __restrict__ UcB) {
  const int nBh = RHOT * DIM;            // 393216
  const int nBm = RF * DIM;              // 425984
  const int nUh = KHOT * RHOT;           // 393216
  const int nUc = (VOUT - KHOT) * RCOLD; // 1575456
  const int total = nBm + nUh + nUc;
  for (int i = blockIdx.x * blockDim.x + threadIdx.x; i < total;
       i += gridDim.x * blockDim.x) {
    if (i < nBm) {
      float v = (i < nBh) ? Bh[i] : Bc[i - nBh];
      Bmat[i] = __float2bfloat16(v);
    } else if (i < nBm + nUh) {
      UhB[i - nBm] = __float2bfloat16(Uh[i - nBm]);
    } else {
      int j = i - nBm - nUh;
      UcB[j] = __float2bfloat16(Uc[j]);
    }
  }
}

// ---------------- K1: G = Bmat @ Bmat^T  (416x416, K=1024), f32 out ----------------
__global__ __launch_bounds__(256) void k_gram(const __hip_bfloat16* __restrict__ Bmat,
                                              float* __restrict__ G) {
  const int wave = threadIdx.x >> 6;
  const int lane = threadIdx.x & 63;
  const int idx = blockIdx.x * 4 + wave;
  if (idx >= 26 * 26) return;  // wave-uniform
  const int ti = idx / 26, tj = idx % 26;
  const int i0 = ti * 16, j0 = tj * 16;
  const int col16 = lane & 15;
  const int g4 = lane >> 4;

  f32x4 acc = (f32x4){0.f, 0.f, 0.f, 0.f};
  const __hip_bfloat16* arow = Bmat + (size_t)(i0 + col16) * DIM;
  const __hip_bfloat16* brow = Bmat + (size_t)(j0 + col16) * DIM;
#pragma unroll 4
  for (int ks = 0; ks < DIM / 32; ++ks) {
    short8 a = *reinterpret_cast<const short8*>(arow + ks * 32 + g4 * 8);
    short8 b = *reinterpret_cast<const short8*>(brow + ks * 32 + g4 * 8);
    acc = __builtin_amdgcn_mfma_f32_16x16x32_bf16(a, b, acc, 0, 0, 0);
  }
#pragma unroll
  for (int r = 0; r < 4; ++r)
    G[(size_t)(i0 + g4 * 4 + r) * RF + j0 + col16] = acc[r];
}

// ---------------- K2: per-token F[n] = u @ G  (f32 math, bf16 out) ----------------
__global__ void k_encode(const int* __restrict__ tokens, const int* __restrict__ o2n,
                         const float* __restrict__ Uh, const float* __restrict__ Uc,
                         const float* __restrict__ G, __hip_bfloat16* __restrict__ F) {
  const int n = blockIdx.x;
  __shared__ float u[RHOT];
  const int tok = tokens[n];
  const int tn = o2n[tok];
  const bool hot = tn < KHOT;
  const int R = hot ? RHOT : RCOLD;
  const float* urow = hot ? (Uh + (size_t)tn * RHOT) : (Uc + (size_t)(tn - KHOT) * RCOLD);
  for (int r = threadIdx.x; r < R; r += blockDim.x) u[r] = urow[r];
  __syncthreads();
  const int gbase = hot ? 0 : RHOT;
  for (int c = threadIdx.x; c < RF; c += blockDim.x) {
    float acc = 0.f;
    for (int r = 0; r < R; ++r) acc += u[r] * G[(size_t)(gbase + r) * RF + c];
    F[(size_t)n * RF + c] = __float2bfloat16(acc);
  }
}

// ---------------- K3 v7: 16 full rows per block, 1024 threads, ping-pong epilogue ----------------
// Grid = 256 blocks. 16 waves; window = 1024 cols (50 windows).
// Compute: wave w computes 4 col-subtiles (cols win*1024 + w*64 + k*16), 16 rows,
// scale+bias folded, into Epi[b]. Store: wave w stores ROW w's 4KB window as 4
// contiguous dwordx4 insts. Loop: {store win from b; compute win+1 into b^1; barrier}.
// Stores issue at phase top -> barrier's vmcnt drain is cheap; compute hides acks.
// Each row's 201KB is one temporally-sequential stream (amp ~1.0 proven in v6).
#define CW 1024
#define RPB 16
#define FPITCH 424   // Fs pitch (bf16)
#define EPITCH 1028  // Epi pitch (f32)

__global__ __launch_bounds__(1024, 4) void k_out(const int* __restrict__ o2n,
                                                 const __hip_bfloat16* __restrict__ F,
                                                 const __hip_bfloat16* __restrict__ Uh,
                                                 const __hip_bfloat16* __restrict__ Uc,
                                                 const float* __restrict__ log_alpha,
                                                 const float* __restrict__ bias,
                                                 float* __restrict__ out) {
  __shared__ __hip_bfloat16 Fs[RPB][FPITCH];   // 13.6 KB
  __shared__ float Epi[2][RPB][EPITCH];        // 131.6 KB
  const int tid = threadIdx.x;
  const int wave = tid >> 6;   // 0..15 = compute col-strip owner AND store row owner
  const int lane = tid & 63;
  const int col16 = lane & 15;
  const int g4 = lane >> 4;
  const int n0 = blockIdx.x * RPB;
  const float alpha = expf(log_alpha[0]);
  const short8 zero8 = (short8){0, 0, 0, 0, 0, 0, 0, 0};

  // stage F slice: 16 rows x 416 cols (52 short8-chunks per row)
  for (int idx = tid; idx < RPB * 52; idx += 1024) {
    const int row = idx / 52, ch = idx % 52;
    *reinterpret_cast<short8*>(&Fs[row][ch * 8]) =
        *reinterpret_cast<const short8*>(F + (size_t)(n0 + row) * RF + ch * 8);
  }
  __syncthreads();

  const int NW = (VOUT + CW - 1) / CW;  // 50

  auto compute = [&](int win, int b) {
    const int cbase = win * CW + wave * 64;
    int srcs[4];
    float bvk[4];
#pragma unroll
    for (int k = 0; k < 4; ++k) {
      const int v = cbase + k * 16 + col16;
      const int vc = (v < VOUT) ? v : (VOUT - 1);
      srcs[k] = o2n[vc];
      bvk[k] = bias[vc];
    }
    unsigned hotm = 0, coldm = 0;
#pragma unroll
    for (int k = 0; k < 4; ++k) {
      if (__any(srcs[k] < KHOT)) hotm |= (1u << k);
      if (__any(srcs[k] >= KHOT)) coldm |= (1u << k);
    }
    f32x4 acc[4];
#pragma unroll
    for (int k = 0; k < 4; ++k) acc[k] = (f32x4){0.f, 0.f, 0.f, 0.f};

    // cold: K = 32, A-frag from Fs
    {
      const short8 afc = *reinterpret_cast<const short8*>(&Fs[col16][RHOT + g4 * 8]);
#pragma unroll
      for (int k = 0; k < 4; ++k) {
        if (coldm & (1u << k)) {
          short8 bfrag = zero8;
          if (srcs[k] >= KHOT)
            bfrag = *reinterpret_cast<const short8*>(
                Uc + (size_t)(srcs[k] - KHOT) * RCOLD + g4 * 8);
          acc[k] = __builtin_amdgcn_mfma_f32_16x16x32_bf16(afc, bfrag, acc[k], 0, 0, 0);
        }
      }
    }
    // hot: K = 384 (rare windows)
    if (hotm) {
      for (int ks = 0; ks < RHOT / 32; ++ks) {
        const short8 afh = *reinterpret_cast<const short8*>(&Fs[col16][ks * 32 + g4 * 8]);
#pragma unroll
        for (int k = 0; k < 4; ++k) {
          if (hotm & (1u << k)) {
            short8 bfrag = zero8;
            if (srcs[k] < KHOT)
              bfrag = *reinterpret_cast<const short8*>(
                  Uh + (size_t)srcs[k] * RHOT + ks * 32 + g4 * 8);
            acc[k] = __builtin_amdgcn_mfma_f32_16x16x32_bf16(afh, bfrag, acc[k], 0, 0, 0);
          }
        }
      }
    }
    // fold scale+bias, write transposed into Epi[b]
#pragma unroll
    for (int k = 0; k < 4; ++k)
#pragma unroll
      for (int r = 0; r < 4; ++r)
        Epi[b][g4 * 4 + r][wave * 64 + k * 16 + col16] = acc[k][r] * alpha + bvk[k];
  };

  compute(0, 0);
  __syncthreads();

  const size_t gr = (size_t)(n0 + wave) * VOUT;
  for (int win = 0; win < NW; ++win) {
    const int b = win & 1;
    // store window win: wave w stores row w, 4KB contiguous
#pragma unroll
    for (int j = 0; j < 4; ++j) {
      const int cc = j * 256 + (lane << 2);
      f32x4 vals = *reinterpret_cast<const f32x4*>(&Epi[b][wave][cc]);
      const int c = win * CW + cc;
      if (c + 3 < VOUT) {
        *reinterpret_cast<f32x4*>(out + gr + c) = vals;
      } else {
#pragma unroll
        for (int q = 0; q < 4; ++q)
          if (c + q < VOUT) out[gr + c + q] = vals[q];
      }
    }
    if (win + 1 < NW) compute(win + 1, b ^ 1);
    __syncthreads();
  }
}

extern "C" void kernel_launch(void* const* d_in, const int* in_sizes, int n_in,
                              void* d_out, int out_size, void* d_ws, size_t ws_size,
                              hipStream_t stream) {
  const int* tokens    = (const int*)d_in[0];
  const int* o2n       = (const int*)d_in[1];
  const float* B_hot   = (const float*)d_in[2];
  const float* B_cold  = (const float*)d_in[3];
  const float* U_hot   = (const float*)d_in[4];
  const float* U_cold  = (const float*)d_in[5];
  const float* log_a   = (const float*)d_in[6];
  const float* bias    = (const float*)d_in[7];
  float* out = (float*)d_out;

  const int N = in_sizes[0];  // 4096 tokens

  // workspace layout (bytes)
  char* ws = (char*)d_ws;
  __hip_bfloat16* Bmat = (__hip_bfloat16*)(ws + 0);             // 425984*2
  __hip_bfloat16* UhB  = (__hip_bfloat16*)(ws + (1u << 20));    // 393216*2
  __hip_bfloat16* UcB  = (__hip_bfloat16*)(ws + (2u << 20));    // 1575456*2
  float*          G    = (float*)(ws + (6u << 20));             // 416*416*4
  __hip_bfloat16* F    = (__hip_bfloat16*)(ws + (7u << 20));    // 4096*416*2

  k_convert<<<2048, 256, 0, stream>>>(B_hot, B_cold, U_hot, U_cold, Bmat, UhB, UcB);
  k_gram<<<169, 256, 0, stream>>>(Bmat, G);
  k_encode<<<N, 256, 0, stream>>>(tokens, o2n, U_hot, U_cold, G, F);

  k_out<<<N / RPB, 1024, 0, stream>>>(o2n, F, UhB, UcB, log_a, bias, out);
}